// Round 22
// baseline (93.675 us; speedup 1.0000x reference)
//
#include <hip/hip_runtime.h>
#include <math.h>

// NoisyTopkRouter: B=4,S=4096,D=2048,E=64,TOP_K=8
//   r22: ZERO-LDS ZERO-BARRIER register GEMM. All 11 prior variants (74-95us)
//   shared one invariant: A staged through LDS with a block barrier per
//   K-step; per-step overhead never moved. Here each wave owns 32 rows x all
//   128 cols and streams BOTH operands to registers (x: 2x16B/lane/step;
//   Wpk repacked [blk16k][part][col][16] -> 8x16B perfectly coalesced,
//   L2-hot). 12 MFMA / 16-k step, bsplit in-reg, waves fully independent.
//   KSPLIT=8 -> 4096 waves = 16/CU. epi_fast sums 8 partials; refine frozen.

#define KDIM 2048
#define NEXP 64
#define TAU 1.5e-4f

typedef __attribute__((ext_vector_type(8))) short short8v;
typedef __attribute__((ext_vector_type(16))) float f32x16;

__device__ __forceinline__ void bsplit(float v, ushort& h, ushort& l) {
  unsigned u = __float_as_uint(v);
  unsigned hu = (u + 0x8000u) & 0xFFFF0000u;
  h = (ushort)(hu >> 16);
  float r = v - __uint_as_float(hu);
  l = (ushort)((__float_as_uint(r) + 0x8000u) >> 16);
}

// Wpk[blk 0..127 (16-k)][part hi/lo][col 0..127][k16] bf16 (1 MB total)
// element (col, k): blk = k>>4, half = (k>>3)&1, j = k&7
// addr = ((blk*2+p)*128 + col)*16 + half*8 + j
__global__ __launch_bounds__(256)
void convert_w(const float* __restrict__ Wr, const float* __restrict__ Wn,
               ushort* __restrict__ Wpk, int* __restrict__ flagcnt) {
  if (blockIdx.x == 0 && threadIdx.x == 0) *flagcnt = 0;
  const int g = blockIdx.x * 256 + threadIdx.x;   // 32768 threads, 8 elems each
  const int col = g >> 8;                         // 0..127
  const int kq  = g & 255;                        // k = kq*8
  const int blk  = kq >> 1;
  const int half = kq & 1;
  const float* srcrow = (col < NEXP) ? (Wr + (size_t)col * KDIM)
                                     : (Wn + (size_t)(col - NEXP) * KDIM);
  const int k = kq * 8;
  const float4 v0 = *(const float4*)(srcrow + k);
  const float4 v1 = *(const float4*)(srcrow + k + 4);
  ushort4 h0, l0, h1, l1;
  bsplit(v0.x, h0.x, l0.x); bsplit(v0.y, h0.y, l0.y);
  bsplit(v0.z, h0.z, l0.z); bsplit(v0.w, h0.w, l0.w);
  bsplit(v1.x, h1.x, l1.x); bsplit(v1.y, h1.y, l1.y);
  bsplit(v1.z, h1.z, l1.z); bsplit(v1.w, h1.w, l1.w);
  const size_t bh = ((size_t)(blk * 2 + 0) * 128 + col) * 16 + half * 8;
  const size_t bl = ((size_t)(blk * 2 + 1) * 128 + col) * 16 + half * 8;
  *(ushort4*)(Wpk + bh)     = h0;
  *(ushort4*)(Wpk + bh + 4) = h1;
  *(ushort4*)(Wpk + bl)     = l0;
  *(ushort4*)(Wpk + bl + 4) = l1;
}

// block = 256 thr (4 waves x 32 rows = 128 rows); grid = (M/128, KSPLIT)
__global__ __launch_bounds__(256, 4)
void gemm_k1(const float* __restrict__ x, const ushort* __restrict__ Wpk,
             float* __restrict__ partials, int M)   // [nsplit][M][128]
{
  const int tid  = threadIdx.x;
  const int wid  = tid >> 6;
  const int lane = tid & 63;
  const int l31  = lane & 31;
  const int kg   = lane >> 5;

  const int row0   = blockIdx.x * 128 + wid * 32;
  const int ks     = blockIdx.y;
  const int nspl   = gridDim.y;
  const int kchunk = KDIM / nspl;                 // 256 at nsplit=8
  const int NST    = kchunk / 16;                 // 16-k steps

  // A stream: lane reads x[row0 + l31][ks*kchunk + s*16 + kg*8 + 0..7]
  const float* xr = x + (size_t)(row0 + l31) * KDIM + (size_t)ks * kchunk + kg * 8;
  // B stream: frag(s, p, c) at Wpk + (((ks*NST+s)*2+p)*128 + c*32 + l31)*16 + kg*8
  const ushort* wb = Wpk + ((size_t)(ks * NST) * 2 * 128 + l31) * 16 + kg * 8;

  f32x16 acc0 = {0,0,0,0,0,0,0,0,0,0,0,0,0,0,0,0};
  f32x16 acc1 = {0,0,0,0,0,0,0,0,0,0,0,0,0,0,0,0};
  f32x16 acc2 = {0,0,0,0,0,0,0,0,0,0,0,0,0,0,0,0};
  f32x16 acc3 = {0,0,0,0,0,0,0,0,0,0,0,0,0,0,0,0};

#pragma unroll 2
  for (int s = 0; s < NST; ++s) {
    const float4 a0 = *(const float4*)(xr + s * 16);
    const float4 a1 = *(const float4*)(xr + s * 16 + 4);
    const ushort* wbs = wb + (size_t)s * 2 * 128 * 16;
    const short8v bh0 = *(const short8v*)(wbs + 0 * 512);
    const short8v bh1 = *(const short8v*)(wbs + 1 * 512);
    const short8v bh2 = *(const short8v*)(wbs + 2 * 512);
    const short8v bh3 = *(const short8v*)(wbs + 3 * 512);
    const short8v bl0 = *(const short8v*)(wbs + 2048 + 0 * 512);
    const short8v bl1 = *(const short8v*)(wbs + 2048 + 1 * 512);
    const short8v bl2 = *(const short8v*)(wbs + 2048 + 2 * 512);
    const short8v bl3 = *(const short8v*)(wbs + 2048 + 3 * 512);

    short8v ah, al; ushort h, l;
    bsplit(a0.x, h, l); ah[0] = h; al[0] = l;
    bsplit(a0.y, h, l); ah[1] = h; al[1] = l;
    bsplit(a0.z, h, l); ah[2] = h; al[2] = l;
    bsplit(a0.w, h, l); ah[3] = h; al[3] = l;
    bsplit(a1.x, h, l); ah[4] = h; al[4] = l;
    bsplit(a1.y, h, l); ah[5] = h; al[5] = l;
    bsplit(a1.z, h, l); ah[6] = h; al[6] = l;
    bsplit(a1.w, h, l); ah[7] = h; al[7] = l;

    acc0 = __builtin_amdgcn_mfma_f32_32x32x16_bf16(ah, bh0, acc0, 0, 0, 0);
    acc1 = __builtin_amdgcn_mfma_f32_32x32x16_bf16(ah, bh1, acc1, 0, 0, 0);
    acc2 = __builtin_amdgcn_mfma_f32_32x32x16_bf16(ah, bh2, acc2, 0, 0, 0);
    acc3 = __builtin_amdgcn_mfma_f32_32x32x16_bf16(ah, bh3, acc3, 0, 0, 0);
    acc0 = __builtin_amdgcn_mfma_f32_32x32x16_bf16(ah, bl0, acc0, 0, 0, 0);
    acc1 = __builtin_amdgcn_mfma_f32_32x32x16_bf16(ah, bl1, acc1, 0, 0, 0);
    acc2 = __builtin_amdgcn_mfma_f32_32x32x16_bf16(ah, bl2, acc2, 0, 0, 0);
    acc3 = __builtin_amdgcn_mfma_f32_32x32x16_bf16(ah, bl3, acc3, 0, 0, 0);
    acc0 = __builtin_amdgcn_mfma_f32_32x32x16_bf16(al, bh0, acc0, 0, 0, 0);
    acc1 = __builtin_amdgcn_mfma_f32_32x32x16_bf16(al, bh1, acc1, 0, 0, 0);
    acc2 = __builtin_amdgcn_mfma_f32_32x32x16_bf16(al, bh2, acc2, 0, 0, 0);
    acc3 = __builtin_amdgcn_mfma_f32_32x32x16_bf16(al, bh3, acc3, 0, 0, 0);
  }

  // C/D layout (32x32): col = lane&31, row = (reg&3) + 8*(reg>>2) + 4*kg
  float* dst = partials + (size_t)ks * M * 128;
#pragma unroll
  for (int reg = 0; reg < 16; ++reg) {
    const int row = (reg & 3) + 8 * (reg >> 2) + 4 * kg;
    float* p = dst + (size_t)(row0 + row) * 128 + l31;
    p[0]  = acc0[reg];
    p[32] = acc1[reg];
    p[64] = acc2[reg];
    p[96] = acc3[reg];
  }
}

// one wave per token: fast path; sums nsplit partials inline
__global__ __launch_bounds__(512, 4)
void epi_fast(const float* __restrict__ partials, int M, int nsplit,
              const float* __restrict__ br, const float* __restrict__ bn,
              const float* __restrict__ noise,
              float* __restrict__ out_w, float* __restrict__ out_i,
              float* __restrict__ out_s,
              int* __restrict__ flagcnt, int* __restrict__ flaglist)
{
  const int wid  = threadIdx.x >> 6;
  const int lane = threadIdx.x & 63;
  const int t    = blockIdx.x * 8 + wid;

  float sr = 0.f, sn = 0.f;
  for (int p = 0; p < nsplit; ++p) {
    sr += partials[(size_t)p * M * 128 + (size_t)t * 128 + lane];
    sn += partials[(size_t)p * M * 128 + (size_t)t * 128 + 64 + lane];
  }
  const float z  = sn + bn[lane];
  const float sp = fmaxf(z, 0.f) + log1pf(expf(-fabsf(z)));
  const float v  = sr + br[lane] + noise[(size_t)t * NEXP + lane] * sp;

  float m = v;
#pragma unroll
  for (int d = 32; d; d >>= 1) m = fmaxf(m, __shfl_xor(m, d));
  const float p = expf(v - m);
  float sum = p;
#pragma unroll
  for (int d = 32; d; d >>= 1) sum += __shfl_xor(sum, d);
  out_s[(size_t)t * NEXP + lane] = p / sum;

  float cur = v;
  float vals9[9]; int idx9[9];
#pragma unroll
  for (int it = 0; it < 9; ++it) {
    float mx = cur;
#pragma unroll
    for (int d = 32; d; d >>= 1) mx = fmaxf(mx, __shfl_xor(mx, d));
    const unsigned long long b = __ballot(cur == mx);
    const int li = __ffsll(b) - 1;                 // ties -> lowest index
    vals9[it] = mx; idx9[it] = li;
    if (lane == li) cur = -INFINITY;
  }
  bool flagged = false;
#pragma unroll
  for (int q = 0; q < 8; ++q) flagged |= (vals9[q] - vals9[q + 1] < TAU);

  if (flagged) {
    if (lane == 0) {
      const int s = atomicAdd(flagcnt, 1);
      flaglist[s] = t;
    }
    return;                                        // refine_* writes outputs
  }

  float pt[8]; float ws = 0.f;
#pragma unroll
  for (int q = 0; q < 8; ++q) { pt[q] = expf(vals9[q] - m); ws += pt[q]; }
  if (lane < 8) {
    out_w[(size_t)t * 8 + lane] = pt[lane] / ws;
    out_i[(size_t)t * 8 + lane] = (float)idx9[lane];
  }
}

// one WAVE per (flagged token, expert): nf*64 wave-jobs, grid-strided
__global__ __launch_bounds__(512)
void refine_dots(const float* __restrict__ x,
                 const float* __restrict__ Wr, const float* __restrict__ Wn,
                 const float* __restrict__ br, const float* __restrict__ bn,
                 const float* __restrict__ noise,
                 const int* __restrict__ flagcnt, const int* __restrict__ flaglist,
                 double* __restrict__ nv64)
{
  const int nf    = *flagcnt;
  const int lane  = threadIdx.x & 63;
  const int wslot = (blockIdx.x * 512 + threadIdx.x) >> 6;
  const int nwav  = (gridDim.x * 512) >> 6;
  const int total = nf * 64;

  for (int w = wslot; w < total; w += nwav) {
    const int i = w >> 6, e = w & 63;
    const int t = flaglist[i];
    const float* xr  = x  + (size_t)t * KDIM + lane * 4;
    const float* wrr = Wr + (size_t)e * KDIM + lane * 4;
    const float* wnr = Wn + (size_t)e * KDIM + lane * 4;
    double a0 = 0, a1 = 0, c0 = 0, c1 = 0;
#pragma unroll
    for (int q = 0; q < 8; ++q) {
      const float4 xv = *(const float4*)(xr  + q * 256);
      const float4 wv = *(const float4*)(wrr + q * 256);
      const float4 nv = *(const float4*)(wnr + q * 256);
      a0 = fma((double)xv.x, (double)wv.x, a0);
      a1 = fma((double)xv.y, (double)wv.y, a1);
      a0 = fma((double)xv.z, (double)wv.z, a0);
      a1 = fma((double)xv.w, (double)wv.w, a1);
      c0 = fma((double)xv.x, (double)nv.x, c0);
      c1 = fma((double)xv.y, (double)nv.y, c1);
      c0 = fma((double)xv.z, (double)nv.z, c0);
      c1 = fma((double)xv.w, (double)nv.w, c1);
    }
    double ar = a0 + a1, an = c0 + c1;
#pragma unroll
    for (int d = 32; d; d >>= 1) {
      ar += __shfl_xor(ar, d);
      an += __shfl_xor(an, d);
    }
    if (lane == 0) {
      const double rte = ar + (double)br[e];
      const double zz  = an + (double)bn[e];
      const double spd = fmax(zz, 0.0) + log1p(exp(-fabs(zz)));
      nv64[(size_t)i * 64 + e] = rte + (double)noise[(size_t)t * NEXP + e] * spd;
    }
  }
}

// one wave per flagged token: proven fp64 softmax/top-8 tail
__global__ __launch_bounds__(512)
void refine_final(const double* __restrict__ nv64,
                  const int* __restrict__ flagcnt, const int* __restrict__ flaglist,
                  float* __restrict__ out_w, float* __restrict__ out_i,
                  float* __restrict__ out_s)
{
  const int nf    = *flagcnt;
  const int lane  = threadIdx.x & 63;
  const int wslot = (blockIdx.x * 512 + threadIdx.x) >> 6;
  const int nwav  = (gridDim.x * 512) >> 6;

  for (int i = wslot; i < nf; i += nwav) {
    const int t = flaglist[i];
    const double v64 = nv64[(size_t)i * 64 + lane];
    double md = v64;
#pragma unroll
    for (int d = 32; d; d >>= 1) md = fmax(md, __shfl_xor(md, d));
    const double pe = exp(v64 - md);
    double sd = pe;
#pragma unroll
    for (int d = 32; d; d >>= 1) sd += __shfl_xor(sd, d);
    out_s[(size_t)t * NEXP + lane] = (float)(pe / sd);

    double curd = v64;
    double pv8[8]; int pi8[8]; double wsd = 0.0;
#pragma unroll
    for (int it = 0; it < 8; ++it) {
      double mx = curd;
#pragma unroll
      for (int d = 32; d; d >>= 1) mx = fmax(mx, __shfl_xor(mx, d));
      const unsigned long long b = __ballot(curd == mx);
      const int li = __ffsll(b) - 1;
      pv8[it] = __shfl(pe, li); pi8[it] = li; wsd += pv8[it];
      if (lane == li) curd = -1e300;
    }
    if (lane < 8) {
      out_w[(size_t)t * 8 + lane] = (float)(pv8[lane] / wsd);
      out_i[(size_t)t * 8 + lane] = (float)pi8[lane];
    }
  }
}

extern "C" void kernel_launch(void* const* d_in, const int* in_sizes, int n_in,
                              void* d_out, int out_size, void* d_ws, size_t ws_size,
                              hipStream_t stream) {
  const float* x     = (const float*)d_in[0];
  const float* Wr    = (const float*)d_in[1];
  const float* br    = (const float*)d_in[2];
  const float* Wn    = (const float*)d_in[3];
  const float* bn    = (const float*)d_in[4];
  const float* noise = (const float*)d_in[5];

  const int M = in_sizes[0] / KDIM;                  // 16384 tokens

  const size_t fixed = (1 << 20) + ((size_t)M + 1) * 4;
  int nsplit = 2;
  if (ws_size >= (size_t)8 * M * 128 * 4 + fixed) nsplit = 8;
  else if (ws_size >= (size_t)4 * M * 128 * 4 + fixed) nsplit = 4;

  float*  partials = (float*)d_ws;                   // [nsplit][M][128]
  double* nv64     = (double*)d_ws;                  // aliases (dead after epi)
  ushort* Wpk      = (ushort*)(partials + (size_t)nsplit * M * 128);  // 1 MB
  int*    flagcnt  = (int*)(Wpk + (size_t)128 * 2 * 128 * 16);
  int*    flaglist = flagcnt + 1;

  float* out   = (float*)d_out;
  float* out_w = out;                                // [M,8]
  float* out_i = out + (size_t)M * 8;                // [M,8] indices as floats
  float* out_s = out + (size_t)M * 16;               // [M,64]

  convert_w<<<dim3(128), dim3(256), 0, stream>>>(Wr, Wn, Wpk, flagcnt);
  gemm_k1<<<dim3(M / 128, nsplit), dim3(256), 0, stream>>>(x, Wpk, partials, M);
  epi_fast<<<dim3(M / 8), dim3(512), 0, stream>>>(partials, M, nsplit, br, bn,
                                                  noise, out_w, out_i, out_s,
                                                  flagcnt, flaglist);
  refine_dots<<<dim3(1024), dim3(512), 0, stream>>>(x, Wr, Wn, br, bn, noise,
                                                    flagcnt, flaglist, nv64);
  refine_final<<<dim3(256), dim3(512), 0, stream>>>(nv64, flagcnt, flaglist,
                                                    out_w, out_i, out_s);
}

// Round 23
// 82.379 us; speedup vs baseline: 1.1371x; 1.1371x over previous
//
#include <hip/hip_runtime.h>
#include <math.h>

// NoisyTopkRouter: B=4,S=4096,D=2048,E=64,TOP_K=8
//   gemm_k1: r23 = r21 (best, 82.2us total: BM=256, KSPLIT=4, counted-vmcnt
//   depth-2 pipeline, 3 LDS buffer sets, raw s_barrier) + T5 s_setprio(1)
//   around the MFMA cluster. r21's schedule is phase-split with wave role
//   diversity -> T5's proven regime (+21-39% on counted-vmcnt GEMM, m218b;
//   null on lockstep, m190). Single change vs r21.
//   convert_w / epi_fast / refine_dots / refine_final frozen (r12/r19).

#define KDIM 2048
#define NEXP 64
#define BM 256
#define KB 32
#define TAU 1.5e-4f

typedef __attribute__((ext_vector_type(8))) short short8v;
typedef __attribute__((ext_vector_type(16))) float f32x16;

__device__ __forceinline__ void bsplit(float v, ushort& h, ushort& l) {
  unsigned u = __float_as_uint(v);
  unsigned hu = (u + 0x8000u) & 0xFFFF0000u;
  h = (ushort)(hu >> 16);
  float r = v - __uint_as_float(hu);
  l = (ushort)((__float_as_uint(r) + 0x8000u) >> 16);
}

// Wpk[blk 0..63][col 0..127][unit' 0..7][8 bf16]; unit' = (p*4+u) ^ (col&7)
__global__ __launch_bounds__(256)
void convert_w(const float* __restrict__ Wr, const float* __restrict__ Wn,
               ushort* __restrict__ Wpk, int* __restrict__ flagcnt) {
  if (blockIdx.x == 0 && threadIdx.x == 0) *flagcnt = 0;
  const int g = blockIdx.x * 256 + threadIdx.x;   // 32768 threads
  const int col = g >> 8;
  const int rem = g & 255;
  const int blk = rem >> 2;
  const int u   = rem & 3;
  const float* srcrow = (col < NEXP) ? (Wr + (size_t)col * KDIM)
                                     : (Wn + (size_t)(col - NEXP) * KDIM);
  const int k = blk * 32 + u * 8;
  const float4 v0 = *(const float4*)(srcrow + k);
  const float4 v1 = *(const float4*)(srcrow + k + 4);
  short8v hv, lv; ushort h, l;
  bsplit(v0.x, h, l); hv[0] = h; lv[0] = l;
  bsplit(v0.y, h, l); hv[1] = h; lv[1] = l;
  bsplit(v0.z, h, l); hv[2] = h; lv[2] = l;
  bsplit(v0.w, h, l); hv[3] = h; lv[3] = l;
  bsplit(v1.x, h, l); hv[4] = h; lv[4] = l;
  bsplit(v1.y, h, l); hv[5] = h; lv[5] = l;
  bsplit(v1.z, h, l); hv[6] = h; lv[6] = l;
  bsplit(v1.w, h, l); hv[7] = h; lv[7] = l;
  const size_t base = (size_t)blk * 8192 + (size_t)col * 64;
  *(short8v*)(Wpk + base + (size_t)((u)     ^ (col & 7)) * 8) = hv;
  *(short8v*)(Wpk + base + (size_t)((4 + u) ^ (col & 7)) * 8) = lv;
}

__global__ __launch_bounds__(512, 1)
void gemm_k1(const float* __restrict__ x, const ushort* __restrict__ Wpk,
             float* __restrict__ partials, int M)   // [nsplit][M][128]
{
  __shared__ ushort Bb[3][8192];    // 3 x 16KB
  __shared__ ushort Ab[3][16384];   // 3 x 32KB   (total 144 KB)

  const int tid   = threadIdx.x;
  const int row0  = blockIdx.x * BM;
  const int ks    = blockIdx.y;
  const int nspl  = gridDim.y;
  const int kchunk = KDIM / nspl;
  const int NKB   = kchunk / KB;               // 16 at nsplit=4
  const ushort* Wpkh = Wpk + (size_t)ks * NKB * 8192;

  const int wid  = tid >> 6;
  const int lane = tid & 63;
  const int l31  = lane & 31;
  const int kg   = lane >> 5;

  const float* xbase = x + (size_t)ks * kchunk;

  const int rr = wid * 32 + l31;
  const int fa = ((l31 & 1) << 2) | ((l31 >> 1) & 3);

  f32x16 acc[4];
#pragma unroll
  for (int c = 0; c < 4; ++c) acc[c] = (f32x16){0,0,0,0,0,0,0,0,0,0,0,0,0,0,0,0};

#define AROW(j)  (((j) * 512 + tid) >> 3)
#define AK4(j)   ((((j) * 512 + tid) & 7) * 4)
#define AFW(j)   (((AROW(j) & 1) << 2) | ((AROW(j) >> 1) & 3))
#define AUNIT(j) (AK4(j) >> 3)
#define AHALF(j) ((AK4(j) >> 2) & 1)

#define SPLIT_STORE(j, xq, buf)                                               \
  do {                                                                        \
    ushort4 hq, lq;                                                           \
    bsplit(xq.x, hq.x, lq.x); bsplit(xq.y, hq.y, lq.y);                       \
    bsplit(xq.z, hq.z, lq.z); bsplit(xq.w, hq.w, lq.w);                       \
    *(ushort4*)&Ab[buf][AROW(j) * 64 + ((AUNIT(j)) ^ AFW(j)) * 8 +            \
                        AHALF(j) * 4] = hq;                                   \
    *(ushort4*)&Ab[buf][AROW(j) * 64 + ((4 + AUNIT(j)) ^ AFW(j)) * 8 +        \
                        AHALF(j) * 4] = lq;                                   \
  } while (0)

#define XADDR(j, s) (xbase + (size_t)(row0 + AROW(j)) * KDIM + (s) * KB + AK4(j))

#define ISSUE_B(t, bidx)                                                      \
  do {                                                                        \
    _Pragma("unroll")                                                         \
    for (int j = 0; j < 2; ++j) {                                             \
      const int idx = j * 512 + tid;                                          \
      __builtin_amdgcn_global_load_lds(                                       \
          (const __attribute__((address_space(1))) void*)                     \
              (Wpkh + (size_t)(t) * 8192 + (size_t)idx * 8),                  \
          (__attribute__((address_space(3))) void*)                           \
              (&Bb[bidx][(size_t)idx * 8]), 16, 0, 0);                        \
    }                                                                         \
  } while (0)

#define COMPUTE(bc)                                                           \
  do {                                                                        \
    __builtin_amdgcn_s_setprio(1);                                            \
    _Pragma("unroll")                                                         \
    for (int kk = 0; kk < 2; ++kk) {                                          \
      const int u = kk * 2 + kg;                                              \
      const short8v ah = *(const short8v*)&Ab[bc][rr * 64 + ((u)     ^ fa) * 8]; \
      const short8v al = *(const short8v*)&Ab[bc][rr * 64 + ((4 + u) ^ fa) * 8]; \
      _Pragma("unroll")                                                       \
      for (int c = 0; c < 4; ++c) {                                           \
        const int colB = c * 32 + l31;                                        \
        const int fb   = colB & 7;                                            \
        const short8v bh = *(const short8v*)&Bb[bc][colB * 64 + ((u)     ^ fb) * 8]; \
        const short8v bl = *(const short8v*)&Bb[bc][colB * 64 + ((4 + u) ^ fb) * 8]; \
        acc[c] = __builtin_amdgcn_mfma_f32_32x32x16_bf16(ah, bh, acc[c], 0, 0, 0);  \
        acc[c] = __builtin_amdgcn_mfma_f32_32x32x16_bf16(ah, bl, acc[c], 0, 0, 0);  \
        acc[c] = __builtin_amdgcn_mfma_f32_32x32x16_bf16(al, bh, acc[c], 0, 0, 0);  \
      }                                                                       \
    }                                                                         \
    __builtin_amdgcn_s_setprio(0);                                            \
  } while (0)

  float4 xe0, xe1, xe2, xe3;   // even reg set
  float4 xo0, xo1, xo2, xo3;   // odd  reg set

  // ---- prologue: batches 0 (->set e) and 1 (->set o) in flight ----
  ISSUE_B(0, 0);
  xe0 = *(const float4*)XADDR(0, 0);
  xe1 = *(const float4*)XADDR(1, 0);
  xe2 = *(const float4*)XADDR(2, 0);
  xe3 = *(const float4*)XADDR(3, 0);
  ISSUE_B(1, 1);
  xo0 = *(const float4*)XADDR(0, 1);
  xo1 = *(const float4*)XADDR(1, 1);
  xo2 = *(const float4*)XADDR(2, 1);
  xo3 = *(const float4*)XADDR(3, 1);
  __builtin_amdgcn_sched_barrier(0);
  asm volatile("s_waitcnt vmcnt(6)" ::: "memory");   // batch 0 home
  __builtin_amdgcn_sched_barrier(0);
  SPLIT_STORE(0, xe0, 0);
  SPLIT_STORE(1, xe1, 0);
  SPLIT_STORE(2, xe2, 0);
  SPLIT_STORE(3, xe3, 0);
  asm volatile("s_waitcnt lgkmcnt(0)" ::: "memory");
  __builtin_amdgcn_s_barrier();
  __builtin_amdgcn_sched_barrier(0);

  for (int ss = 0; ss < NKB; ss += 2) {
    // ======== even step s = ss: issue(s+2)->set e; consume set o ========
    {
      const int s  = ss;
      const int bc = s % 3, bw = (s + 1) % 3, bi = (s + 2) % 3;
      if (s + 2 < NKB) {
        ISSUE_B(s + 2, bi);
        xe0 = *(const float4*)XADDR(0, s + 2);
        xe1 = *(const float4*)XADDR(1, s + 2);
        xe2 = *(const float4*)XADDR(2, s + 2);
        xe3 = *(const float4*)XADDR(3, s + 2);
      }
      __builtin_amdgcn_sched_barrier(0);
      COMPUTE(bc);
      __builtin_amdgcn_sched_barrier(0);
      if (s + 2 < NKB) {
        asm volatile("s_waitcnt vmcnt(6)" ::: "memory");
      } else if (s + 1 < NKB) {
        asm volatile("s_waitcnt vmcnt(0)" ::: "memory");
      }
      __builtin_amdgcn_sched_barrier(0);
      if (s + 1 < NKB) {
        SPLIT_STORE(0, xo0, bw);
        SPLIT_STORE(1, xo1, bw);
        SPLIT_STORE(2, xo2, bw);
        SPLIT_STORE(3, xo3, bw);
      }
      asm volatile("s_waitcnt lgkmcnt(0)" ::: "memory");
      __builtin_amdgcn_s_barrier();
      __builtin_amdgcn_sched_barrier(0);
    }
    // ======== odd step s = ss+1: issue(s+2)->set o; consume set e ========
    {
      const int s  = ss + 1;
      const int bc = s % 3, bw = (s + 1) % 3, bi = (s + 2) % 3;
      if (s + 2 < NKB) {
        ISSUE_B(s + 2, bi);
        xo0 = *(const float4*)XADDR(0, s + 2);
        xo1 = *(const float4*)XADDR(1, s + 2);
        xo2 = *(const float4*)XADDR(2, s + 2);
        xo3 = *(const float4*)XADDR(3, s + 2);
      }
      __builtin_amdgcn_sched_barrier(0);
      COMPUTE(bc);
      __builtin_amdgcn_sched_barrier(0);
      if (s + 2 < NKB) {
        asm volatile("s_waitcnt vmcnt(6)" ::: "memory");
      } else if (s + 1 < NKB) {
        asm volatile("s_waitcnt vmcnt(0)" ::: "memory");
      }
      __builtin_amdgcn_sched_barrier(0);
      if (s + 1 < NKB) {
        SPLIT_STORE(0, xe0, bw);
        SPLIT_STORE(1, xe1, bw);
        SPLIT_STORE(2, xe2, bw);
        SPLIT_STORE(3, xe3, bw);
      }
      asm volatile("s_waitcnt lgkmcnt(0)" ::: "memory");
      __builtin_amdgcn_s_barrier();
      __builtin_amdgcn_sched_barrier(0);
    }
  }
#undef COMPUTE
#undef ISSUE_B
#undef SPLIT_STORE
#undef XADDR
#undef AROW
#undef AK4
#undef AFW
#undef AUNIT
#undef AHALF

  // C/D layout (32x32): col = lane&31, row = (reg&3) + 8*(reg>>2) + 4*kg
  float* dst = partials + (size_t)ks * M * 128;
#pragma unroll
  for (int c = 0; c < 4; ++c)
#pragma unroll
    for (int reg = 0; reg < 16; ++reg) {
      const int row = (reg & 3) + 8 * (reg >> 2) + 4 * kg;
      dst[(size_t)(row0 + wid * 32 + row) * 128 + c * 32 + l31] = acc[c][reg];
    }
}

// one wave per token: fast path; sums nsplit partials inline
__global__ __launch_bounds__(512, 4)
void epi_fast(const float* __restrict__ partials, int M, int nsplit,
              const float* __restrict__ br, const float* __restrict__ bn,
              const float* __restrict__ noise,
              float* __restrict__ out_w, float* __restrict__ out_i,
              float* __restrict__ out_s,
              int* __restrict__ flagcnt, int* __restrict__ flaglist)
{
  const int wid  = threadIdx.x >> 6;
  const int lane = threadIdx.x & 63;
  const int t    = blockIdx.x * 8 + wid;

  float sr = 0.f, sn = 0.f;
  for (int p = 0; p < nsplit; ++p) {
    sr += partials[(size_t)p * M * 128 + (size_t)t * 128 + lane];
    sn += partials[(size_t)p * M * 128 + (size_t)t * 128 + 64 + lane];
  }
  const float z  = sn + bn[lane];
  const float sp = fmaxf(z, 0.f) + log1pf(expf(-fabsf(z)));
  const float v  = sr + br[lane] + noise[(size_t)t * NEXP + lane] * sp;

  float m = v;
#pragma unroll
  for (int d = 32; d; d >>= 1) m = fmaxf(m, __shfl_xor(m, d));
  const float p = expf(v - m);
  float sum = p;
#pragma unroll
  for (int d = 32; d; d >>= 1) sum += __shfl_xor(sum, d);
  out_s[(size_t)t * NEXP + lane] = p / sum;

  float cur = v;
  float vals9[9]; int idx9[9];
#pragma unroll
  for (int it = 0; it < 9; ++it) {
    float mx = cur;
#pragma unroll
    for (int d = 32; d; d >>= 1) mx = fmaxf(mx, __shfl_xor(mx, d));
    const unsigned long long b = __ballot(cur == mx);
    const int li = __ffsll(b) - 1;                 // ties -> lowest index
    vals9[it] = mx; idx9[it] = li;
    if (lane == li) cur = -INFINITY;
  }
  bool flagged = false;
#pragma unroll
  for (int q = 0; q < 8; ++q) flagged |= (vals9[q] - vals9[q + 1] < TAU);

  if (flagged) {
    if (lane == 0) {
      const int s = atomicAdd(flagcnt, 1);
      flaglist[s] = t;
    }
    return;                                        // refine_* writes outputs
  }

  float pt[8]; float ws = 0.f;
#pragma unroll
  for (int q = 0; q < 8; ++q) { pt[q] = expf(vals9[q] - m); ws += pt[q]; }
  if (lane < 8) {
    out_w[(size_t)t * 8 + lane] = pt[lane] / ws;
    out_i[(size_t)t * 8 + lane] = (float)idx9[lane];
  }
}

// one WAVE per (flagged token, expert): nf*64 wave-jobs, grid-strided
__global__ __launch_bounds__(512)
void refine_dots(const float* __restrict__ x,
                 const float* __restrict__ Wr, const float* __restrict__ Wn,
                 const float* __restrict__ br, const float* __restrict__ bn,
                 const float* __restrict__ noise,
                 const int* __restrict__ flagcnt, const int* __restrict__ flaglist,
                 double* __restrict__ nv64)
{
  const int nf    = *flagcnt;
  const int lane  = threadIdx.x & 63;
  const int wslot = (blockIdx.x * 512 + threadIdx.x) >> 6;
  const int nwav  = (gridDim.x * 512) >> 6;
  const int total = nf * 64;

  for (int w = wslot; w < total; w += nwav) {
    const int i = w >> 6, e = w & 63;
    const int t = flaglist[i];
    const float* xr  = x  + (size_t)t * KDIM + lane * 4;
    const float* wrr = Wr + (size_t)e * KDIM + lane * 4;
    const float* wnr = Wn + (size_t)e * KDIM + lane * 4;
    double a0 = 0, a1 = 0, c0 = 0, c1 = 0;
#pragma unroll
    for (int q = 0; q < 8; ++q) {
      const float4 xv = *(const float4*)(xr  + q * 256);
      const float4 wv = *(const float4*)(wrr + q * 256);
      const float4 nv = *(const float4*)(wnr + q * 256);
      a0 = fma((double)xv.x, (double)wv.x, a0);
      a1 = fma((double)xv.y, (double)wv.y, a1);
      a0 = fma((double)xv.z, (double)wv.z, a0);
      a1 = fma((double)xv.w, (double)wv.w, a1);
      c0 = fma((double)xv.x, (double)nv.x, c0);
      c1 = fma((double)xv.y, (double)nv.y, c1);
      c0 = fma((double)xv.z, (double)nv.z, c0);
      c1 = fma((double)xv.w, (double)nv.w, c1);
    }
    double ar = a0 + a1, an = c0 + c1;
#pragma unroll
    for (int d = 32; d; d >>= 1) {
      ar += __shfl_xor(ar, d);
      an += __shfl_xor(an, d);
    }
    if (lane == 0) {
      const double rte = ar + (double)br[e];
      const double zz  = an + (double)bn[e];
      const double spd = fmax(zz, 0.0) + log1p(exp(-fabs(zz)));
      nv64[(size_t)i * 64 + e] = rte + (double)noise[(size_t)t * NEXP + e] * spd;
    }
  }
}

// one wave per flagged token: proven fp64 softmax/top-8 tail
__global__ __launch_bounds__(512)
void refine_final(const double* __restrict__ nv64,
                  const int* __restrict__ flagcnt, const int* __restrict__ flaglist,
                  float* __restrict__ out_w, float* __restrict__ out_i,
                  float* __restrict__ out_s)
{
  const int nf    = *flagcnt;
  const int lane  = threadIdx.x & 63;
  const int wslot = (blockIdx.x * 512 + threadIdx.x) >> 6;
  const int nwav  = (gridDim.x * 512) >> 6;

  for (int i = wslot; i < nf; i += nwav) {
    const int t = flaglist[i];
    const double v64 = nv64[(size_t)i * 64 + lane];
    double md = v64;
#pragma unroll
    for (int d = 32; d; d >>= 1) md = fmax(md, __shfl_xor(md, d));
    const double pe = exp(v64 - md);
    double sd = pe;
#pragma unroll
    for (int d = 32; d; d >>= 1) sd += __shfl_xor(sd, d);
    out_s[(size_t)t * NEXP + lane] = (float)(pe / sd);

    double curd = v64;
    double pv8[8]; int pi8[8]; double wsd = 0.0;
#pragma unroll
    for (int it = 0; it < 8; ++it) {
      double mx = curd;
#pragma unroll
      for (int d = 32; d; d >>= 1) mx = fmax(mx, __shfl_xor(mx, d));
      const unsigned long long b = __ballot(curd == mx);
      const int li = __ffsll(b) - 1;
      pv8[it] = __shfl(pe, li); pi8[it] = li; wsd += pv8[it];
      if (lane == li) curd = -1e300;
    }
    if (lane < 8) {
      out_w[(size_t)t * 8 + lane] = (float)(pv8[lane] / wsd);
      out_i[(size_t)t * 8 + lane] = (float)pi8[lane];
    }
  }
}

extern "C" void kernel_launch(void* const* d_in, const int* in_sizes, int n_in,
                              void* d_out, int out_size, void* d_ws, size_t ws_size,
                              hipStream_t stream) {
  const float* x     = (const float*)d_in[0];
  const float* Wr    = (const float*)d_in[1];
  const float* br    = (const float*)d_in[2];
  const float* Wn    = (const float*)d_in[3];
  const float* bn    = (const float*)d_in[4];
  const float* noise = (const float*)d_in[5];

  const int M = in_sizes[0] / KDIM;                  // 16384 tokens

  const size_t fixed = (1 << 20) + ((size_t)M + 1) * 4;
  int nsplit = 2;
  if (ws_size >= (size_t)4 * M * 128 * 4 + fixed) nsplit = 4;

  float*  partials = (float*)d_ws;                   // [nsplit][M][128]
  double* nv64     = (double*)d_ws;                  // aliases (dead after epi)
  ushort* Wpk      = (ushort*)(partials + (size_t)nsplit * M * 128);  // 1 MB
  int*    flagcnt  = (int*)(Wpk + (size_t)64 * 8192);
  int*    flaglist = flagcnt + 1;

  float* out   = (float*)d_out;
  float* out_w = out;                                // [M,8]
  float* out_i = out + (size_t)M * 8;                // [M,8] indices as floats
  float* out_s = out + (size_t)M * 16;               // [M,64]

  convert_w<<<dim3(128), dim3(256), 0, stream>>>(Wr, Wn, Wpk, flagcnt);
  gemm_k1<<<dim3(M / BM, nsplit), dim3(512), 0, stream>>>(x, Wpk, partials, M);
  epi_fast<<<dim3(M / 8), dim3(512), 0, stream>>>(partials, M, nsplit, br, bn,
                                                  noise, out_w, out_i, out_s,
                                                  flagcnt, flaglist);
  refine_dots<<<dim3(1024), dim3(512), 0, stream>>>(x, Wr, Wn, br, bn, noise,
                                                    flagcnt, flaglist, nv64);
  refine_final<<<dim3(256), dim3(512), 0, stream>>>(nv64, flagcnt, flaglist,
                                                    out_w, out_i, out_s);
}

// Round 24
// 79.788 us; speedup vs baseline: 1.1741x; 1.0325x over previous
//
#include <hip/hip_runtime.h>
#include <math.h>

// NoisyTopkRouter: B=4,S=4096,D=2048,E=64,TOP_K=8
//   gemm_k1: r24 = r23 counted-vmcnt template with BM 256->128 so LDS drops
//   144->80KB -> 2 blocks/CU (r23 ran 1 blk/CU; r16 showed block overlap is
//   the only lever that paid). A: 2 buffer sets (writes land post-vmcnt, one
//   barrier from readers). B: 3 sets. Batch = 4 VMEM/thread -> steady
//   vmcnt(4). Wave = 32 rows x 64 cols (2 acc, ~90 VGPR, cap 128).
//   convert_w / epi_fast / refine_dots / refine_final frozen (r12/r19).

#define KDIM 2048
#define NEXP 64
#define BM 128
#define KB 32
#define TAU 1.5e-4f

typedef __attribute__((ext_vector_type(8))) short short8v;
typedef __attribute__((ext_vector_type(16))) float f32x16;

__device__ __forceinline__ void bsplit(float v, ushort& h, ushort& l) {
  unsigned u = __float_as_uint(v);
  unsigned hu = (u + 0x8000u) & 0xFFFF0000u;
  h = (ushort)(hu >> 16);
  float r = v - __uint_as_float(hu);
  l = (ushort)((__float_as_uint(r) + 0x8000u) >> 16);
}

// Wpk[blk 0..63][col 0..127][unit' 0..7][8 bf16]; unit' = (p*4+u) ^ (col&7)
__global__ __launch_bounds__(256)
void convert_w(const float* __restrict__ Wr, const float* __restrict__ Wn,
               ushort* __restrict__ Wpk, int* __restrict__ flagcnt) {
  if (blockIdx.x == 0 && threadIdx.x == 0) *flagcnt = 0;
  const int g = blockIdx.x * 256 + threadIdx.x;   // 32768 threads
  const int col = g >> 8;
  const int rem = g & 255;
  const int blk = rem >> 2;
  const int u   = rem & 3;
  const float* srcrow = (col < NEXP) ? (Wr + (size_t)col * KDIM)
                                     : (Wn + (size_t)(col - NEXP) * KDIM);
  const int k = blk * 32 + u * 8;
  const float4 v0 = *(const float4*)(srcrow + k);
  const float4 v1 = *(const float4*)(srcrow + k + 4);
  short8v hv, lv; ushort h, l;
  bsplit(v0.x, h, l); hv[0] = h; lv[0] = l;
  bsplit(v0.y, h, l); hv[1] = h; lv[1] = l;
  bsplit(v0.z, h, l); hv[2] = h; lv[2] = l;
  bsplit(v0.w, h, l); hv[3] = h; lv[3] = l;
  bsplit(v1.x, h, l); hv[4] = h; lv[4] = l;
  bsplit(v1.y, h, l); hv[5] = h; lv[5] = l;
  bsplit(v1.z, h, l); hv[6] = h; lv[6] = l;
  bsplit(v1.w, h, l); hv[7] = h; lv[7] = l;
  const size_t base = (size_t)blk * 8192 + (size_t)col * 64;
  *(short8v*)(Wpk + base + (size_t)((u)     ^ (col & 7)) * 8) = hv;
  *(short8v*)(Wpk + base + (size_t)((4 + u) ^ (col & 7)) * 8) = lv;
}

__global__ __launch_bounds__(512, 4)
void gemm_k1(const float* __restrict__ x, const ushort* __restrict__ Wpk,
             float* __restrict__ partials, int M)   // [nsplit][M][128]
{
  __shared__ ushort Bb[3][8192];    // 3 x 16KB  (B, DMA depth-2)
  __shared__ ushort Ab[2][8192];    // 2 x 16KB  (A [row128][unit'8][8])

  const int tid   = threadIdx.x;
  const int row0  = blockIdx.x * BM;
  const int ks    = blockIdx.y;
  const int nspl  = gridDim.y;
  const int kchunk = KDIM / nspl;
  const int NKB   = kchunk / KB;               // 16 at nsplit=4
  const ushort* Wpkh = Wpk + (size_t)ks * NKB * 8192;

  const int wid  = tid >> 6;            // 8 waves: rg = wid>>1, ch = wid&1
  const int lane = tid & 63;
  const int l31  = lane & 31;
  const int kg   = lane >> 5;
  const int rg   = wid >> 1;            // row-group 0..3 (32 rows)
  const int ch   = wid & 1;             // col-half 0/1 (64 cols)

  const float* xbase = x + (size_t)ks * kchunk;

  const int rr = rg * 32 + l31;
  const int fa = ((l31 & 1) << 2) | ((l31 >> 1) & 3);

  f32x16 acc0 = {0,0,0,0,0,0,0,0,0,0,0,0,0,0,0,0};
  f32x16 acc1 = {0,0,0,0,0,0,0,0,0,0,0,0,0,0,0,0};

#define AROW(j)  (((j) * 512 + tid) >> 3)          // j=0,1 -> rows 0..127
#define AK4(j)   ((((j) * 512 + tid) & 7) * 4)
#define AFW(j)   (((AROW(j) & 1) << 2) | ((AROW(j) >> 1) & 3))
#define AUNIT(j) (AK4(j) >> 3)
#define AHALF(j) ((AK4(j) >> 2) & 1)

#define SPLIT_STORE(j, xq, buf)                                               \
  do {                                                                        \
    ushort4 hq, lq;                                                           \
    bsplit(xq.x, hq.x, lq.x); bsplit(xq.y, hq.y, lq.y);                       \
    bsplit(xq.z, hq.z, lq.z); bsplit(xq.w, hq.w, lq.w);                       \
    *(ushort4*)&Ab[buf][AROW(j) * 64 + ((AUNIT(j)) ^ AFW(j)) * 8 +            \
                        AHALF(j) * 4] = hq;                                   \
    *(ushort4*)&Ab[buf][AROW(j) * 64 + ((4 + AUNIT(j)) ^ AFW(j)) * 8 +        \
                        AHALF(j) * 4] = lq;                                   \
  } while (0)

#define XADDR(j, s) (xbase + (size_t)(row0 + AROW(j)) * KDIM + (s) * KB + AK4(j))

#define ISSUE_B(t, bidx)                                                      \
  do {                                                                        \
    _Pragma("unroll")                                                         \
    for (int j = 0; j < 2; ++j) {                                             \
      const int idx = j * 512 + tid;                                          \
      __builtin_amdgcn_global_load_lds(                                       \
          (const __attribute__((address_space(1))) void*)                     \
              (Wpkh + (size_t)(t) * 8192 + (size_t)idx * 8),                  \
          (__attribute__((address_space(3))) void*)                           \
              (&Bb[bidx][(size_t)idx * 8]), 16, 0, 0);                        \
    }                                                                         \
  } while (0)

#define COMPUTE(bcA, bcB)                                                     \
  do {                                                                        \
    __builtin_amdgcn_s_setprio(1);                                            \
    _Pragma("unroll")                                                         \
    for (int kk = 0; kk < 2; ++kk) {                                          \
      const int u = kk * 2 + kg;                                              \
      const short8v ah = *(const short8v*)&Ab[bcA][rr * 64 + ((u)     ^ fa) * 8]; \
      const short8v al = *(const short8v*)&Ab[bcA][rr * 64 + ((4 + u) ^ fa) * 8]; \
      {                                                                       \
        const int colB = ch * 64 + l31;                                       \
        const int fb   = colB & 7;                                            \
        const short8v bh = *(const short8v*)&Bb[bcB][colB * 64 + ((u)     ^ fb) * 8]; \
        const short8v bl = *(const short8v*)&Bb[bcB][colB * 64 + ((4 + u) ^ fb) * 8]; \
        acc0 = __builtin_amdgcn_mfma_f32_32x32x16_bf16(ah, bh, acc0, 0, 0, 0);      \
        acc0 = __builtin_amdgcn_mfma_f32_32x32x16_bf16(ah, bl, acc0, 0, 0, 0);      \
        acc0 = __builtin_amdgcn_mfma_f32_32x32x16_bf16(al, bh, acc0, 0, 0, 0);      \
      }                                                                       \
      {                                                                       \
        const int colB = ch * 64 + 32 + l31;                                  \
        const int fb   = colB & 7;                                            \
        const short8v bh = *(const short8v*)&Bb[bcB][colB * 64 + ((u)     ^ fb) * 8]; \
        const short8v bl = *(const short8v*)&Bb[bcB][colB * 64 + ((4 + u) ^ fb) * 8]; \
        acc1 = __builtin_amdgcn_mfma_f32_32x32x16_bf16(ah, bh, acc1, 0, 0, 0);      \
        acc1 = __builtin_amdgcn_mfma_f32_32x32x16_bf16(ah, bl, acc1, 0, 0, 0);      \
        acc1 = __builtin_amdgcn_mfma_f32_32x32x16_bf16(al, bh, acc1, 0, 0, 0);      \
      }                                                                       \
    }                                                                         \
    __builtin_amdgcn_s_setprio(0);                                            \
  } while (0)

  float4 xe0, xe1;   // even reg set
  float4 xo0, xo1;   // odd  reg set

  // ---- prologue: batches 0 (->e) and 1 (->o) in flight (4 VMEM each) ----
  ISSUE_B(0, 0);
  xe0 = *(const float4*)XADDR(0, 0);
  xe1 = *(const float4*)XADDR(1, 0);
  ISSUE_B(1, 1);
  xo0 = *(const float4*)XADDR(0, 1);
  xo1 = *(const float4*)XADDR(1, 1);
  __builtin_amdgcn_sched_barrier(0);
  asm volatile("s_waitcnt vmcnt(4)" ::: "memory");   // batch 0 home
  __builtin_amdgcn_sched_barrier(0);
  SPLIT_STORE(0, xe0, 0);
  SPLIT_STORE(1, xe1, 0);
  asm volatile("s_waitcnt lgkmcnt(0)" ::: "memory");
  __builtin_amdgcn_s_barrier();
  __builtin_amdgcn_sched_barrier(0);

  for (int ss = 0; ss < NKB; ss += 2) {
    // ======== even step s = ss: issue(s+2)->e; consume x set o ========
    {
      const int s   = ss;
      const int bcA = s & 1,   bwA = (s + 1) & 1;
      const int bcB = s % 3,   bi  = (s + 2) % 3;
      if (s + 2 < NKB) {
        ISSUE_B(s + 2, bi);
        xe0 = *(const float4*)XADDR(0, s + 2);
        xe1 = *(const float4*)XADDR(1, s + 2);
      }
      __builtin_amdgcn_sched_barrier(0);
      COMPUTE(bcA, bcB);
      __builtin_amdgcn_sched_barrier(0);
      if (s + 2 < NKB) {
        asm volatile("s_waitcnt vmcnt(4)" ::: "memory");
      } else if (s + 1 < NKB) {
        asm volatile("s_waitcnt vmcnt(0)" ::: "memory");
      }
      __builtin_amdgcn_sched_barrier(0);
      if (s + 1 < NKB) {
        SPLIT_STORE(0, xo0, bwA);
        SPLIT_STORE(1, xo1, bwA);
      }
      asm volatile("s_waitcnt lgkmcnt(0)" ::: "memory");
      __builtin_amdgcn_s_barrier();
      __builtin_amdgcn_sched_barrier(0);
    }
    // ======== odd step s = ss+1: issue(s+2)->o; consume x set e ========
    {
      const int s   = ss + 1;
      const int bcA = s & 1,   bwA = (s + 1) & 1;
      const int bcB = s % 3,   bi  = (s + 2) % 3;
      if (s + 2 < NKB) {
        ISSUE_B(s + 2, bi);
        xo0 = *(const float4*)XADDR(0, s + 2);
        xo1 = *(const float4*)XADDR(1, s + 2);
      }
      __builtin_amdgcn_sched_barrier(0);
      COMPUTE(bcA, bcB);
      __builtin_amdgcn_sched_barrier(0);
      if (s + 2 < NKB) {
        asm volatile("s_waitcnt vmcnt(4)" ::: "memory");
      } else if (s + 1 < NKB) {
        asm volatile("s_waitcnt vmcnt(0)" ::: "memory");
      }
      __builtin_amdgcn_sched_barrier(0);
      if (s + 1 < NKB) {
        SPLIT_STORE(0, xe0, bwA);
        SPLIT_STORE(1, xe1, bwA);
      }
      asm volatile("s_waitcnt lgkmcnt(0)" ::: "memory");
      __builtin_amdgcn_s_barrier();
      __builtin_amdgcn_sched_barrier(0);
    }
  }
#undef COMPUTE
#undef ISSUE_B
#undef SPLIT_STORE
#undef XADDR
#undef AROW
#undef AK4
#undef AFW
#undef AUNIT
#undef AHALF

  // C/D layout (32x32): col = lane&31, row = (reg&3) + 8*(reg>>2) + 4*kg
  float* dst = partials + (size_t)ks * M * 128;
#pragma unroll
  for (int reg = 0; reg < 16; ++reg) {
    const int row = (reg & 3) + 8 * (reg >> 2) + 4 * kg;
    float* p = dst + (size_t)(row0 + rg * 32 + row) * 128 + ch * 64 + l31;
    p[0]  = acc0[reg];
    p[32] = acc1[reg];
  }
}

// one wave per token: fast path; sums nsplit partials inline
__global__ __launch_bounds__(512, 4)
void epi_fast(const float* __restrict__ partials, int M, int nsplit,
              const float* __restrict__ br, const float* __restrict__ bn,
              const float* __restrict__ noise,
              float* __restrict__ out_w, float* __restrict__ out_i,
              float* __restrict__ out_s,
              int* __restrict__ flagcnt, int* __restrict__ flaglist)
{
  const int wid  = threadIdx.x >> 6;
  const int lane = threadIdx.x & 63;
  const int t    = blockIdx.x * 8 + wid;

  float sr = 0.f, sn = 0.f;
  for (int p = 0; p < nsplit; ++p) {
    sr += partials[(size_t)p * M * 128 + (size_t)t * 128 + lane];
    sn += partials[(size_t)p * M * 128 + (size_t)t * 128 + 64 + lane];
  }
  const float z  = sn + bn[lane];
  const float sp = fmaxf(z, 0.f) + log1pf(expf(-fabsf(z)));
  const float v  = sr + br[lane] + noise[(size_t)t * NEXP + lane] * sp;

  float m = v;
#pragma unroll
  for (int d = 32; d; d >>= 1) m = fmaxf(m, __shfl_xor(m, d));
  const float p = expf(v - m);
  float sum = p;
#pragma unroll
  for (int d = 32; d; d >>= 1) sum += __shfl_xor(sum, d);
  out_s[(size_t)t * NEXP + lane] = p / sum;

  float cur = v;
  float vals9[9]; int idx9[9];
#pragma unroll
  for (int it = 0; it < 9; ++it) {
    float mx = cur;
#pragma unroll
    for (int d = 32; d; d >>= 1) mx = fmaxf(mx, __shfl_xor(mx, d));
    const unsigned long long b = __ballot(cur == mx);
    const int li = __ffsll(b) - 1;                 // ties -> lowest index
    vals9[it] = mx; idx9[it] = li;
    if (lane == li) cur = -INFINITY;
  }
  bool flagged = false;
#pragma unroll
  for (int q = 0; q < 8; ++q) flagged |= (vals9[q] - vals9[q + 1] < TAU);

  if (flagged) {
    if (lane == 0) {
      const int s = atomicAdd(flagcnt, 1);
      flaglist[s] = t;
    }
    return;                                        // refine_* writes outputs
  }

  float pt[8]; float ws = 0.f;
#pragma unroll
  for (int q = 0; q < 8; ++q) { pt[q] = expf(vals9[q] - m); ws += pt[q]; }
  if (lane < 8) {
    out_w[(size_t)t * 8 + lane] = pt[lane] / ws;
    out_i[(size_t)t * 8 + lane] = (float)idx9[lane];
  }
}

// one WAVE per (flagged token, expert): nf*64 wave-jobs, grid-strided
__global__ __launch_bounds__(512)
void refine_dots(const float* __restrict__ x,
                 const float* __restrict__ Wr, const float* __restrict__ Wn,
                 const float* __restrict__ br, const float* __restrict__ bn,
                 const float* __restrict__ noise,
                 const int* __restrict__ flagcnt, const int* __restrict__ flaglist,
                 double* __restrict__ nv64)
{
  const int nf    = *flagcnt;
  const int lane  = threadIdx.x & 63;
  const int wslot = (blockIdx.x * 512 + threadIdx.x) >> 6;
  const int nwav  = (gridDim.x * 512) >> 6;
  const int total = nf * 64;

  for (int w = wslot; w < total; w += nwav) {
    const int i = w >> 6, e = w & 63;
    const int t = flaglist[i];
    const float* xr  = x  + (size_t)t * KDIM + lane * 4;
    const float* wrr = Wr + (size_t)e * KDIM + lane * 4;
    const float* wnr = Wn + (size_t)e * KDIM + lane * 4;
    double a0 = 0, a1 = 0, c0 = 0, c1 = 0;
#pragma unroll
    for (int q = 0; q < 8; ++q) {
      const float4 xv = *(const float4*)(xr  + q * 256);
      const float4 wv = *(const float4*)(wrr + q * 256);
      const float4 nv = *(const float4*)(wnr + q * 256);
      a0 = fma((double)xv.x, (double)wv.x, a0);
      a1 = fma((double)xv.y, (double)wv.y, a1);
      a0 = fma((double)xv.z, (double)wv.z, a0);
      a1 = fma((double)xv.w, (double)wv.w, a1);
      c0 = fma((double)xv.x, (double)nv.x, c0);
      c1 = fma((double)xv.y, (double)nv.y, c1);
      c0 = fma((double)xv.z, (double)nv.z, c0);
      c1 = fma((double)xv.w, (double)nv.w, c1);
    }
    double ar = a0 + a1, an = c0 + c1;
#pragma unroll
    for (int d = 32; d; d >>= 1) {
      ar += __shfl_xor(ar, d);
      an += __shfl_xor(an, d);
    }
    if (lane == 0) {
      const double rte = ar + (double)br[e];
      const double zz  = an + (double)bn[e];
      const double spd = fmax(zz, 0.0) + log1p(exp(-fabs(zz)));
      nv64[(size_t)i * 64 + e] = rte + (double)noise[(size_t)t * NEXP + e] * spd;
    }
  }
}

// one wave per flagged token: proven fp64 softmax/top-8 tail
__global__ __launch_bounds__(512)
void refine_final(const double* __restrict__ nv64,
                  const int* __restrict__ flagcnt, const int* __restrict__ flaglist,
                  float* __restrict__ out_w, float* __restrict__ out_i,
                  float* __restrict__ out_s)
{
  const int nf    = *flagcnt;
  const int lane  = threadIdx.x & 63;
  const int wslot = (blockIdx.x * 512 + threadIdx.x) >> 6;
  const int nwav  = (gridDim.x * 512) >> 6;

  for (int i = wslot; i < nf; i += nwav) {
    const int t = flaglist[i];
    const double v64 = nv64[(size_t)i * 64 + lane];
    double md = v64;
#pragma unroll
    for (int d = 32; d; d >>= 1) md = fmax(md, __shfl_xor(md, d));
    const double pe = exp(v64 - md);
    double sd = pe;
#pragma unroll
    for (int d = 32; d; d >>= 1) sd += __shfl_xor(sd, d);
    out_s[(size_t)t * NEXP + lane] = (float)(pe / sd);

    double curd = v64;
    double pv8[8]; int pi8[8]; double wsd = 0.0;
#pragma unroll
    for (int it = 0; it < 8; ++it) {
      double mx = curd;
#pragma unroll
      for (int d = 32; d; d >>= 1) mx = fmax(mx, __shfl_xor(mx, d));
      const unsigned long long b = __ballot(curd == mx);
      const int li = __ffsll(b) - 1;
      pv8[it] = __shfl(pe, li); pi8[it] = li; wsd += pv8[it];
      if (lane == li) curd = -1e300;
    }
    if (lane < 8) {
      out_w[(size_t)t * 8 + lane] = (float)(pv8[lane] / wsd);
      out_i[(size_t)t * 8 + lane] = (float)pi8[lane];
    }
  }
}

extern "C" void kernel_launch(void* const* d_in, const int* in_sizes, int n_in,
                              void* d_out, int out_size, void* d_ws, size_t ws_size,
                              hipStream_t stream) {
  const float* x     = (const float*)d_in[0];
  const float* Wr    = (const float*)d_in[1];
  const float* br    = (const float*)d_in[2];
  const float* Wn    = (const float*)d_in[3];
  const float* bn    = (const float*)d_in[4];
  const float* noise = (const float*)d_in[5];

  const int M = in_sizes[0] / KDIM;                  // 16384 tokens

  const size_t fixed = (1 << 20) + ((size_t)M + 1) * 4;
  int nsplit = 2;
  if (ws_size >= (size_t)4 * M * 128 * 4 + fixed) nsplit = 4;

  float*  partials = (float*)d_ws;                   // [nsplit][M][128]
  double* nv64     = (double*)d_ws;                  // aliases (dead after epi)
  ushort* Wpk      = (ushort*)(partials + (size_t)nsplit * M * 128);  // 1 MB
  int*    flagcnt  = (int*)(Wpk + (size_t)64 * 8192);
  int*    flaglist = flagcnt + 1;

  float* out   = (float*)d_out;
  float* out_w = out;                                // [M,8]
  float* out_i = out + (size_t)M * 8;                // [M,8] indices as floats
  float* out_s = out + (size_t)M * 16;               // [M,64]

  convert_w<<<dim3(128), dim3(256), 0, stream>>>(Wr, Wn, Wpk, flagcnt);
  gemm_k1<<<dim3(M / BM, nsplit), dim3(512), 0, stream>>>(x, Wpk, partials, M);
  epi_fast<<<dim3(M / 8), dim3(512), 0, stream>>>(partials, M, nsplit, br, bn,
                                                  noise, out_w, out_i, out_s,
                                                  flagcnt, flaglist);
  refine_dots<<<dim3(1024), dim3(512), 0, stream>>>(x, Wr, Wn, br, bn, noise,
                                                    flagcnt, flaglist, nv64);
  refine_final<<<dim3(256), dim3(512), 0, stream>>>(nv64, flagcnt, flaglist,
                                                    out_w, out_i, out_s);
}

// Round 25
// 78.951 us; speedup vs baseline: 1.1865x; 1.0106x over previous
//
#include <hip/hip_runtime.h>
#include <math.h>

// NoisyTopkRouter: B=4,S=4096,D=2048,E=64,TOP_K=8
// FINAL (r24, best: 79.8us). Pipeline:
//   convert_w   : W -> per-K-block bf16 hi/lo LDS-image, baked XOR swizzle
//   gemm_k1     : split-bf16 MFMA GEMM (Ah*Bh+Ah*Bl+Al*Bh, err ~1e-5),
//                 BM=128, KSPLIT=4, counted-vmcnt depth-2 pipeline, 3 B-buf +
//                 2 A-buf LDS sets (80KB -> 2 blocks/CU), raw s_barrier,
//                 steady-state vmcnt(4) (never drains to 0 mid-loop).
//   epi_fast    : one wave/token: partial-sum, softplus, noisy logits,
//                 softmax, ballot top-9 with exact lowest-index ties;
//                 near-ties (gap < TAU) -> device flag list.
//   refine_dots : one WAVE per (flagged token, expert) exact fp64 dots.
//   refine_final: one wave per flagged token fp64 softmax/top-8.
// 24-round trajectory: 294 -> 235 -> 190 -> 108 -> 84 -> 79.8 us.

#define KDIM 2048
#define NEXP 64
#define BM 128
#define KB 32
#define TAU 1.5e-4f

typedef __attribute__((ext_vector_type(8))) short short8v;
typedef __attribute__((ext_vector_type(16))) float f32x16;

__device__ __forceinline__ void bsplit(float v, ushort& h, ushort& l) {
  unsigned u = __float_as_uint(v);
  unsigned hu = (u + 0x8000u) & 0xFFFF0000u;
  h = (ushort)(hu >> 16);
  float r = v - __uint_as_float(hu);
  l = (ushort)((__float_as_uint(r) + 0x8000u) >> 16);
}

// Wpk[blk 0..63][col 0..127][unit' 0..7][8 bf16]; unit' = (p*4+u) ^ (col&7)
__global__ __launch_bounds__(256)
void convert_w(const float* __restrict__ Wr, const float* __restrict__ Wn,
               ushort* __restrict__ Wpk, int* __restrict__ flagcnt) {
  if (blockIdx.x == 0 && threadIdx.x == 0) *flagcnt = 0;
  const int g = blockIdx.x * 256 + threadIdx.x;   // 32768 threads
  const int col = g >> 8;
  const int rem = g & 255;
  const int blk = rem >> 2;
  const int u   = rem & 3;
  const float* srcrow = (col < NEXP) ? (Wr + (size_t)col * KDIM)
                                     : (Wn + (size_t)(col - NEXP) * KDIM);
  const int k = blk * 32 + u * 8;
  const float4 v0 = *(const float4*)(srcrow + k);
  const float4 v1 = *(const float4*)(srcrow + k + 4);
  short8v hv, lv; ushort h, l;
  bsplit(v0.x, h, l); hv[0] = h; lv[0] = l;
  bsplit(v0.y, h, l); hv[1] = h; lv[1] = l;
  bsplit(v0.z, h, l); hv[2] = h; lv[2] = l;
  bsplit(v0.w, h, l); hv[3] = h; lv[3] = l;
  bsplit(v1.x, h, l); hv[4] = h; lv[4] = l;
  bsplit(v1.y, h, l); hv[5] = h; lv[5] = l;
  bsplit(v1.z, h, l); hv[6] = h; lv[6] = l;
  bsplit(v1.w, h, l); hv[7] = h; lv[7] = l;
  const size_t base = (size_t)blk * 8192 + (size_t)col * 64;
  *(short8v*)(Wpk + base + (size_t)((u)     ^ (col & 7)) * 8) = hv;
  *(short8v*)(Wpk + base + (size_t)((4 + u) ^ (col & 7)) * 8) = lv;
}

__global__ __launch_bounds__(512, 4)
void gemm_k1(const float* __restrict__ x, const ushort* __restrict__ Wpk,
             float* __restrict__ partials, int M)   // [nsplit][M][128]
{
  __shared__ ushort Bb[3][8192];    // 3 x 16KB  (B, DMA depth-2)
  __shared__ ushort Ab[2][8192];    // 2 x 16KB  (A [row128][unit'8][8])

  const int tid   = threadIdx.x;
  const int row0  = blockIdx.x * BM;
  const int ks    = blockIdx.y;
  const int nspl  = gridDim.y;
  const int kchunk = KDIM / nspl;
  const int NKB   = kchunk / KB;               // 16 at nsplit=4
  const ushort* Wpkh = Wpk + (size_t)ks * NKB * 8192;

  const int wid  = tid >> 6;            // 8 waves: rg = wid>>1, ch = wid&1
  const int lane = tid & 63;
  const int l31  = lane & 31;
  const int kg   = lane >> 5;
  const int rg   = wid >> 1;            // row-group 0..3 (32 rows)
  const int ch   = wid & 1;             // col-half 0/1 (64 cols)

  const float* xbase = x + (size_t)ks * kchunk;

  const int rr = rg * 32 + l31;
  const int fa = ((l31 & 1) << 2) | ((l31 >> 1) & 3);

  f32x16 acc0 = {0,0,0,0,0,0,0,0,0,0,0,0,0,0,0,0};
  f32x16 acc1 = {0,0,0,0,0,0,0,0,0,0,0,0,0,0,0,0};

#define AROW(j)  (((j) * 512 + tid) >> 3)          // j=0,1 -> rows 0..127
#define AK4(j)   ((((j) * 512 + tid) & 7) * 4)
#define AFW(j)   (((AROW(j) & 1) << 2) | ((AROW(j) >> 1) & 3))
#define AUNIT(j) (AK4(j) >> 3)
#define AHALF(j) ((AK4(j) >> 2) & 1)

#define SPLIT_STORE(j, xq, buf)                                               \
  do {                                                                        \
    ushort4 hq, lq;                                                           \
    bsplit(xq.x, hq.x, lq.x); bsplit(xq.y, hq.y, lq.y);                       \
    bsplit(xq.z, hq.z, lq.z); bsplit(xq.w, hq.w, lq.w);                       \
    *(ushort4*)&Ab[buf][AROW(j) * 64 + ((AUNIT(j)) ^ AFW(j)) * 8 +            \
                        AHALF(j) * 4] = hq;                                   \
    *(ushort4*)&Ab[buf][AROW(j) * 64 + ((4 + AUNIT(j)) ^ AFW(j)) * 8 +        \
                        AHALF(j) * 4] = lq;                                   \
  } while (0)

#define XADDR(j, s) (xbase + (size_t)(row0 + AROW(j)) * KDIM + (s) * KB + AK4(j))

#define ISSUE_B(t, bidx)                                                      \
  do {                                                                        \
    _Pragma("unroll")                                                         \
    for (int j = 0; j < 2; ++j) {                                             \
      const int idx = j * 512 + tid;                                          \
      __builtin_amdgcn_global_load_lds(                                       \
          (const __attribute__((address_space(1))) void*)                     \
              (Wpkh + (size_t)(t) * 8192 + (size_t)idx * 8),                  \
          (__attribute__((address_space(3))) void*)                           \
              (&Bb[bidx][(size_t)idx * 8]), 16, 0, 0);                        \
    }                                                                         \
  } while (0)

#define COMPUTE(bcA, bcB)                                                     \
  do {                                                                        \
    __builtin_amdgcn_s_setprio(1);                                            \
    _Pragma("unroll")                                                         \
    for (int kk = 0; kk < 2; ++kk) {                                          \
      const int u = kk * 2 + kg;                                              \
      const short8v ah = *(const short8v*)&Ab[bcA][rr * 64 + ((u)     ^ fa) * 8]; \
      const short8v al = *(const short8v*)&Ab[bcA][rr * 64 + ((4 + u) ^ fa) * 8]; \
      {                                                                       \
        const int colB = ch * 64 + l31;                                       \
        const int fb   = colB & 7;                                            \
        const short8v bh = *(const short8v*)&Bb[bcB][colB * 64 + ((u)     ^ fb) * 8]; \
        const short8v bl = *(const short8v*)&Bb[bcB][colB * 64 + ((4 + u) ^ fb) * 8]; \
        acc0 = __builtin_amdgcn_mfma_f32_32x32x16_bf16(ah, bh, acc0, 0, 0, 0);      \
        acc0 = __builtin_amdgcn_mfma_f32_32x32x16_bf16(ah, bl, acc0, 0, 0, 0);      \
        acc0 = __builtin_amdgcn_mfma_f32_32x32x16_bf16(al, bh, acc0, 0, 0, 0);      \
      }                                                                       \
      {                                                                       \
        const int colB = ch * 64 + 32 + l31;                                  \
        const int fb   = colB & 7;                                            \
        const short8v bh = *(const short8v*)&Bb[bcB][colB * 64 + ((u)     ^ fb) * 8]; \
        const short8v bl = *(const short8v*)&Bb[bcB][colB * 64 + ((4 + u) ^ fb) * 8]; \
        acc1 = __builtin_amdgcn_mfma_f32_32x32x16_bf16(ah, bh, acc1, 0, 0, 0);      \
        acc1 = __builtin_amdgcn_mfma_f32_32x32x16_bf16(ah, bl, acc1, 0, 0, 0);      \
        acc1 = __builtin_amdgcn_mfma_f32_32x32x16_bf16(al, bh, acc1, 0, 0, 0);      \
      }                                                                       \
    }                                                                         \
    __builtin_amdgcn_s_setprio(0);                                            \
  } while (0)

  float4 xe0, xe1;   // even reg set
  float4 xo0, xo1;   // odd  reg set

  // ---- prologue: batches 0 (->e) and 1 (->o) in flight (4 VMEM each) ----
  ISSUE_B(0, 0);
  xe0 = *(const float4*)XADDR(0, 0);
  xe1 = *(const float4*)XADDR(1, 0);
  ISSUE_B(1, 1);
  xo0 = *(const float4*)XADDR(0, 1);
  xo1 = *(const float4*)XADDR(1, 1);
  __builtin_amdgcn_sched_barrier(0);
  asm volatile("s_waitcnt vmcnt(4)" ::: "memory");   // batch 0 home
  __builtin_amdgcn_sched_barrier(0);
  SPLIT_STORE(0, xe0, 0);
  SPLIT_STORE(1, xe1, 0);
  asm volatile("s_waitcnt lgkmcnt(0)" ::: "memory");
  __builtin_amdgcn_s_barrier();
  __builtin_amdgcn_sched_barrier(0);

  for (int ss = 0; ss < NKB; ss += 2) {
    // ======== even step s = ss: issue(s+2)->e; consume x set o ========
    {
      const int s   = ss;
      const int bcA = s & 1,   bwA = (s + 1) & 1;
      const int bcB = s % 3,   bi  = (s + 2) % 3;
      if (s + 2 < NKB) {
        ISSUE_B(s + 2, bi);
        xe0 = *(const float4*)XADDR(0, s + 2);
        xe1 = *(const float4*)XADDR(1, s + 2);
      }
      __builtin_amdgcn_sched_barrier(0);
      COMPUTE(bcA, bcB);
      __builtin_amdgcn_sched_barrier(0);
      if (s + 2 < NKB) {
        asm volatile("s_waitcnt vmcnt(4)" ::: "memory");
      } else if (s + 1 < NKB) {
        asm volatile("s_waitcnt vmcnt(0)" ::: "memory");
      }
      __builtin_amdgcn_sched_barrier(0);
      if (s + 1 < NKB) {
        SPLIT_STORE(0, xo0, bwA);
        SPLIT_STORE(1, xo1, bwA);
      }
      asm volatile("s_waitcnt lgkmcnt(0)" ::: "memory");
      __builtin_amdgcn_s_barrier();
      __builtin_amdgcn_sched_barrier(0);
    }
    // ======== odd step s = ss+1: issue(s+2)->o; consume x set e ========
    {
      const int s   = ss + 1;
      const int bcA = s & 1,   bwA = (s + 1) & 1;
      const int bcB = s % 3,   bi  = (s + 2) % 3;
      if (s + 2 < NKB) {
        ISSUE_B(s + 2, bi);
        xo0 = *(const float4*)XADDR(0, s + 2);
        xo1 = *(const float4*)XADDR(1, s + 2);
      }
      __builtin_amdgcn_sched_barrier(0);
      COMPUTE(bcA, bcB);
      __builtin_amdgcn_sched_barrier(0);
      if (s + 2 < NKB) {
        asm volatile("s_waitcnt vmcnt(4)" ::: "memory");
      } else if (s + 1 < NKB) {
        asm volatile("s_waitcnt vmcnt(0)" ::: "memory");
      }
      __builtin_amdgcn_sched_barrier(0);
      if (s + 1 < NKB) {
        SPLIT_STORE(0, xe0, bwA);
        SPLIT_STORE(1, xe1, bwA);
      }
      asm volatile("s_waitcnt lgkmcnt(0)" ::: "memory");
      __builtin_amdgcn_s_barrier();
      __builtin_amdgcn_sched_barrier(0);
    }
  }
#undef COMPUTE
#undef ISSUE_B
#undef SPLIT_STORE
#undef XADDR
#undef AROW
#undef AK4
#undef AFW
#undef AUNIT
#undef AHALF

  // C/D layout (32x32): col = lane&31, row = (reg&3) + 8*(reg>>2) + 4*kg
  float* dst = partials + (size_t)ks * M * 128;
#pragma unroll
  for (int reg = 0; reg < 16; ++reg) {
    const int row = (reg & 3) + 8 * (reg >> 2) + 4 * kg;
    float* p = dst + (size_t)(row0 + rg * 32 + row) * 128 + ch * 64 + l31;
    p[0]  = acc0[reg];
    p[32] = acc1[reg];
  }
}

// one wave per token: fast path; sums nsplit partials inline
__global__ __launch_bounds__(512, 4)
void epi_fast(const float* __restrict__ partials, int M, int nsplit,
              const float* __restrict__ br, const float* __restrict__ bn,
              const float* __restrict__ noise,
              float* __restrict__ out_w, float* __restrict__ out_i,
              float* __restrict__ out_s,
              int* __restrict__ flagcnt, int* __restrict__ flaglist)
{
  const int wid  = threadIdx.x >> 6;
  const int lane = threadIdx.x & 63;
  const int t    = blockIdx.x * 8 + wid;

  float sr = 0.f, sn = 0.f;
  for (int p = 0; p < nsplit; ++p) {
    sr += partials[(size_t)p * M * 128 + (size_t)t * 128 + lane];
    sn += partials[(size_t)p * M * 128 + (size_t)t * 128 + 64 + lane];
  }
  const float z  = sn + bn[lane];
  const float sp = fmaxf(z, 0.f) + log1pf(expf(-fabsf(z)));
  const float v  = sr + br[lane] + noise[(size_t)t * NEXP + lane] * sp;

  float m = v;
#pragma unroll
  for (int d = 32; d; d >>= 1) m = fmaxf(m, __shfl_xor(m, d));
  const float p = expf(v - m);
  float sum = p;
#pragma unroll
  for (int d = 32; d; d >>= 1) sum += __shfl_xor(sum, d);
  out_s[(size_t)t * NEXP + lane] = p / sum;

  float cur = v;
  float vals9[9]; int idx9[9];
#pragma unroll
  for (int it = 0; it < 9; ++it) {
    float mx = cur;
#pragma unroll
    for (int d = 32; d; d >>= 1) mx = fmaxf(mx, __shfl_xor(mx, d));
    const unsigned long long b = __ballot(cur == mx);
    const int li = __ffsll(b) - 1;                 // ties -> lowest index
    vals9[it] = mx; idx9[it] = li;
    if (lane == li) cur = -INFINITY;
  }
  bool flagged = false;
#pragma unroll
  for (int q = 0; q < 8; ++q) flagged |= (vals9[q] - vals9[q + 1] < TAU);

  if (flagged) {
    if (lane == 0) {
      const int s = atomicAdd(flagcnt, 1);
      flaglist[s] = t;
    }
    return;                                        // refine_* writes outputs
  }

  float pt[8]; float ws = 0.f;
#pragma unroll
  for (int q = 0; q < 8; ++q) { pt[q] = expf(vals9[q] - m); ws += pt[q]; }
  if (lane < 8) {
    out_w[(size_t)t * 8 + lane] = pt[lane] / ws;
    out_i[(size_t)t * 8 + lane] = (float)idx9[lane];
  }
}

// one WAVE per (flagged token, expert): nf*64 wave-jobs, grid-strided
__global__ __launch_bounds__(512)
void refine_dots(const float* __restrict__ x,
                 const float* __restrict__ Wr, const float* __restrict__ Wn,
                 const float* __restrict__ br, const float* __restrict__ bn,
                 const float* __restrict__ noise,
                 const int* __restrict__ flagcnt, const int* __restrict__ flaglist,
                 double* __restrict__ nv64)
{
  const int nf    = *flagcnt;
  const int lane  = threadIdx.x & 63;
  const int wslot = (blockIdx.x * 512 + threadIdx.x) >> 6;
  const int nwav  = (gridDim.x * 512) >> 6;
  const int total = nf * 64;

  for (int w = wslot; w < total; w += nwav) {
    const int i = w >> 6, e = w & 63;
    const int t = flaglist[i];
    const float* xr  = x  + (size_t)t * KDIM + lane * 4;
    const float* wrr = Wr + (size_t)e * KDIM + lane * 4;
    const float* wnr = Wn + (size_t)e * KDIM + lane * 4;
    double a0 = 0, a1 = 0, c0 = 0, c1 = 0;
#pragma unroll
    for (int q = 0; q < 8; ++q) {
      const float4 xv = *(const float4*)(xr  + q * 256);
      const float4 wv = *(const float4*)(wrr + q * 256);
      const float4 nv = *(const float4*)(wnr + q * 256);
      a0 = fma((double)xv.x, (double)wv.x, a0);
      a1 = fma((double)xv.y, (double)wv.y, a1);
      a0 = fma((double)xv.z, (double)wv.z, a0);
      a1 = fma((double)xv.w, (double)wv.w, a1);
      c0 = fma((double)xv.x, (double)nv.x, c0);
      c1 = fma((double)xv.y, (double)nv.y, c1);
      c0 = fma((double)xv.z, (double)nv.z, c0);
      c1 = fma((double)xv.w, (double)nv.w, c1);
    }
    double ar = a0 + a1, an = c0 + c1;
#pragma unroll
    for (int d = 32; d; d >>= 1) {
      ar += __shfl_xor(ar, d);
      an += __shfl_xor(an, d);
    }
    if (lane == 0) {
      const double rte = ar + (double)br[e];
      const double zz  = an + (double)bn[e];
      const double spd = fmax(zz, 0.0) + log1p(exp(-fabs(zz)));
      nv64[(size_t)i * 64 + e] = rte + (double)noise[(size_t)t * NEXP + e] * spd;
    }
  }
}

// one wave per flagged token: proven fp64 softmax/top-8 tail
__global__ __launch_bounds__(512)
void refine_final(const double* __restrict__ nv64,
                  const int* __restrict__ flagcnt, const int* __restrict__ flaglist,
                  float* __restrict__ out_w, float* __restrict__ out_i,
                  float* __restrict__ out_s)
{
  const int nf    = *flagcnt;
  const int lane  = threadIdx.x & 63;
  const int wslot = (blockIdx.x * 512 + threadIdx.x) >> 6;
  const int nwav  = (gridDim.x * 512) >> 6;

  for (int i = wslot; i < nf; i += nwav) {
    const int t = flaglist[i];
    const double v64 = nv64[(size_t)i * 64 + lane];
    double md = v64;
#pragma unroll
    for (int d = 32; d; d >>= 1) md = fmax(md, __shfl_xor(md, d));
    const double pe = exp(v64 - md);
    double sd = pe;
#pragma unroll
    for (int d = 32; d; d >>= 1) sd += __shfl_xor(sd, d);
    out_s[(size_t)t * NEXP + lane] = (float)(pe / sd);

    double curd = v64;
    double pv8[8]; int pi8[8]; double wsd = 0.0;
#pragma unroll
    for (int it = 0; it < 8; ++it) {
      double mx = curd;
#pragma unroll
      for (int d = 32; d; d >>= 1) mx = fmax(mx, __shfl_xor(mx, d));
      const unsigned long long b = __ballot(curd == mx);
      const int li = __ffsll(b) - 1;
      pv8[it] = __shfl(pe, li); pi8[it] = li; wsd += pv8[it];
      if (lane == li) curd = -1e300;
    }
    if (lane < 8) {
      out_w[(size_t)t * 8 + lane] = (float)(pv8[lane] / wsd);
      out_i[(size_t)t * 8 + lane] = (float)pi8[lane];
    }
  }
}

extern "C" void kernel_launch(void* const* d_in, const int* in_sizes, int n_in,
                              void* d_out, int out_size, void* d_ws, size_t ws_size,
                              hipStream_t stream) {
  const float* x     = (const float*)d_in[0];
  const float* Wr    = (const float*)d_in[1];
  const float* br    = (const float*)d_in[2];
  const float* Wn    = (const float*)d_in[3];
  const float* bn    = (const float*)d_in[4];
  const float* noise = (const float*)d_in[5];

  const int M = in_sizes[0] / KDIM;                  // 16384 tokens

  const size_t fixed = (1 << 20) + ((size_t)M + 1) * 4;
  int nsplit = 2;
  if (ws_size >= (size_t)4 * M * 128 * 4 + fixed) nsplit = 4;

  float*  partials = (float*)d_ws;                   // [nsplit][M][128]
  double* nv64     = (double*)d_ws;                  // aliases (dead after epi)
  ushort* Wpk      = (ushort*)(partials + (size_t)nsplit * M * 128);  // 1 MB
  int*    flagcnt  = (int*)(Wpk + (size_t)64 * 8192);
  int*    flaglist = flagcnt + 1;

  float* out   = (float*)d_out;
  float* out_w = out;                                // [M,8]
  float* out_i = out + (size_t)M * 8;                // [M,8] indices as floats
  float* out_s = out + (size_t)M * 16;               // [M,64]

  convert_w<<<dim3(128), dim3(256), 0, stream>>>(Wr, Wn, Wpk, flagcnt);
  gemm_k1<<<dim3(M / BM, nsplit), dim3(512), 0, stream>>>(x, Wpk, partials, M);
  epi_fast<<<dim3(M / 8), dim3(512), 0, stream>>>(partials, M, nsplit, br, bn,
                                                  noise, out_w, out_i, out_s,
                                                  flagcnt, flaglist);
  refine_dots<<<dim3(1024), dim3(512), 0, stream>>>(x, Wr, Wn, br, bn, noise,
                                                    flagcnt, flaglist, nv64);
  refine_final<<<dim3(256), dim3(512), 0, stream>>>(nv64, flagcnt, flaglist,
                                                    out_w, out_i, out_s);
}